// Round 6
// baseline (1017.870 us; speedup 1.0000x reference)
//
#include <hip/hip_runtime.h>
#include <hip/hip_bf16.h>

typedef unsigned short u16;
typedef unsigned char u8;
typedef unsigned int u32;
typedef __attribute__((ext_vector_type(8))) short short8;
typedef __attribute__((ext_vector_type(4))) float f32x4;

#define B_ 64
#define T_ 512
#define E_ 300
#define KP_ 320
#define H_ 128
#define G_ 512
#define C_ 20
#define NCH_ 32
#define CS_ 16

__device__ __forceinline__ float b2f(u16 u) {
    union { u32 i; float f; } v; v.i = ((u32)u) << 16; return v.f;
}
__device__ __forceinline__ u16 f2b(float f) {
    union { float f; u32 i; } v; v.f = f;
    u32 r = (v.i + 0x7fffu + ((v.i >> 16) & 1u)) >> 16;   // RNE
    return (u16)r;
}
__device__ __forceinline__ float loadf(const void* p, long i, u32 isf32) {
    return isf32 ? ((const float*)p)[i] : b2f(((const u16*)p)[i]);
}
__device__ __forceinline__ float sigmoidf_(float x) {
    return 1.0f / (1.0f + __expf(-x));
}
__device__ __forceinline__ float tanhf_(float x) {
    float cx = fminf(fmaxf(x, -15.f), 15.f);
    float e = __expf(2.f * cx);
    return (e - 1.f) / (e + 1.f);
}
__device__ __forceinline__ int loadmask(const void* m, int idx, u32 isbool) {
    return isbool ? (int)((const u8*)m)[idx] : ((const int*)m)[idx];
}

// ---------------- sniff input dtypes (deterministic, same result every call)
__global__ void sniff_kernel(const u32* __restrict__ emb32,
                             const u32* __restrict__ mask32,
                             u32* __restrict__ flags) {
    if (threadIdx.x == 0) {
        u32 nz = 0;
        for (int i = 150; i < 300; ++i) nz |= emb32[i];
        flags[0] = (nz == 0) ? 1u : 0u;          // f32 floats?
        u32 m0 = mask32[0];
        flags[1] = ((m0 & 0xFFFFFF00u) != 0) ? 1u : 0u;  // bool mask?
    }
}

// ---------------- prep: normalize weights into canonical buffers
__global__ __launch_bounds__(256) void prep_kernel(
    const void* __restrict__ Wihf, const void* __restrict__ Wihb,
    const void* __restrict__ Whhf, const void* __restrict__ Whhb,
    const void* __restrict__ bihf, const void* __restrict__ bhhf,
    const void* __restrict__ bihb, const void* __restrict__ bhhb,
    const void* __restrict__ fcW, const void* __restrict__ fcb,
    const void* __restrict__ trans, const u32* __restrict__ flags,
    u16* __restrict__ Wpad, u16* __restrict__ Whhc, float* __restrict__ biasc,
    u16* __restrict__ fcWc, float* __restrict__ fcbf, float* __restrict__ transf) {
    const u32 isf32 = flags[0];
    int idx = blockIdx.x * 256 + threadIdx.x;
    if (idx < 2 * G_ * KP_) {
        int dir = idx / (G_ * KP_), rem = idx % (G_ * KP_);
        int g = rem / KP_, kp = rem % KP_;
        const void* src = dir ? Wihb : Wihf;
        float v = (kp < E_) ? loadf(src, (long)g * E_ + kp, isf32) : 0.f;
        Wpad[idx] = f2b(v);
        return;
    }
    idx -= 2 * G_ * KP_;
    if (idx < 2 * G_ * H_) {
        int dir = idx >> 16, r = idx & 65535;
        Whhc[idx] = f2b(loadf(dir ? Whhb : Whhf, r, isf32));
        return;
    }
    idx -= 2 * G_ * H_;
    if (idx < 2 * G_) {
        int dir = idx >> 9, g = idx & 511;
        biasc[idx] = loadf(dir ? bihb : bihf, g, isf32) +
                     loadf(dir ? bhhb : bhhf, g, isf32);
        return;
    }
    idx -= 2 * G_;
    if (idx < C_ * 256) { fcWc[idx] = f2b(loadf(fcW, idx, isf32)); return; }
    idx -= C_ * 256;
    if (idx < C_) { fcbf[idx] = loadf(fcb, idx, isf32); return; }
    idx -= C_;
    if (idx < C_ * C_) { transf[idx] = loadf(trans, idx, isf32); return; }
}

// ---------------- chunked xw GEMM with fused embedding gather (dtype-adaptive A).
__global__ __launch_bounds__(256) void gemm_xw(const int* __restrict__ x,
                                               const void* __restrict__ emb,
                                               const u16* __restrict__ Wpad,
                                               const float* __restrict__ biasc,
                                               const u32* __restrict__ flags,
                                               u16* __restrict__ xwf, u16* __restrict__ xwb,
                                               int tclog2, int t0f, int t0b) {
    const int m0 = blockIdx.x * 128;
    const int n0 = blockIdx.y * 128;
    const int dir = blockIdx.z;
    const u16* Bw = Wpad + (size_t)dir * G_ * KP_;
    u16* out = dir ? xwb : xwf;
    const int t0 = dir ? t0b : t0f;
    const int ts = dir ? -1 : 1;
    const int tcm = (1 << tclog2) - 1;
    const u32 isf32 = flags[0];

    __shared__ __align__(16) short As[128 * 32];
    __shared__ __align__(16) short Bs[128 * 32];
    __shared__ int xs[128];

    const int tid = threadIdx.x;
    const int lane = tid & 63;
    const int wave = tid >> 6;
    const int wm = wave & 1, wn = wave >> 1;
    const int lr = lane & 15, lq = lane >> 4;

    if (tid < 128) {
        int i = m0 + tid;
        int b = i >> tclog2;
        int r = i & tcm;
        xs[tid] = x[b * T_ + t0 + ts * r];
    }
    __syncthreads();

    f32x4 acc[4][4];
#pragma unroll
    for (int mt = 0; mt < 4; ++mt)
#pragma unroll
        for (int nt = 0; nt < 4; ++nt)
            acc[mt][nt] = (f32x4){0.f, 0.f, 0.f, 0.f};

    for (int kb = 0; kb < KP_; kb += 32) {
        if (isf32) {
            const float* ef = (const float*)emb;
#pragma unroll
            for (int hh = 0; hh < 4; ++hh) {
                int c = tid + hh * 256;
                int row = c >> 3;
                int k4 = (c & 7) * 4;
                int k = kb + k4;
                uint2 o = make_uint2(0u, 0u);
                if (k < E_) {
                    float4 v = *(const float4*)(ef + (size_t)xs[row] * E_ + k);
                    o.x = (u32)f2b(v.x) | ((u32)f2b(v.y) << 16);
                    o.y = (u32)f2b(v.z) | ((u32)f2b(v.w) << 16);
                }
                *(uint2*)(&As[row * 32 + k4]) = o;
            }
        } else {
            const u16* eb = (const u16*)emb;
#pragma unroll
            for (int hh = 0; hh < 4; ++hh) {
                int c = tid + hh * 256;
                int row = c >> 3;
                int k4 = (c & 7) * 4;
                int k = kb + k4;
                uint2 va = make_uint2(0u, 0u);
                if (k < E_)
                    va = *(const uint2*)(eb + (size_t)xs[row] * E_ + k);
                *(uint2*)(&As[row * 32 + k4]) = va;
            }
        }
#pragma unroll
        for (int hh = 0; hh < 2; ++hh) {
            int c = tid + hh * 256;
            int row = c >> 2;
            int k8 = (c & 3) * 8;
            uint4 vb = *(const uint4*)(Bw + (size_t)(n0 + row) * KP_ + kb + k8);
            *(uint4*)(&Bs[row * 32 + k8]) = vb;
        }
        __syncthreads();
        short8 afr[4], bfr[4];
#pragma unroll
        for (int mt = 0; mt < 4; ++mt)
            afr[mt] = *(const short8*)&As[(wm * 64 + mt * 16 + lr) * 32 + lq * 8];
#pragma unroll
        for (int nt = 0; nt < 4; ++nt)
            bfr[nt] = *(const short8*)&Bs[(wn * 64 + nt * 16 + lr) * 32 + lq * 8];
#pragma unroll
        for (int mt = 0; mt < 4; ++mt)
#pragma unroll
            for (int nt = 0; nt < 4; ++nt)
                acc[mt][nt] = __builtin_amdgcn_mfma_f32_16x16x32_bf16(afr[mt], bfr[nt], acc[mt][nt], 0, 0, 0);
        __syncthreads();
    }
#pragma unroll
    for (int nt = 0; nt < 4; ++nt) {
        int n = n0 + wn * 64 + nt * 16 + lr;
        float bn = biasc[dir * G_ + n];
#pragma unroll
        for (int mt = 0; mt < 4; ++mt) {
            int mbase = m0 + wm * 64 + mt * 16 + lq * 4;
#pragma unroll
            for (int r = 0; r < 4; ++r)
                out[(size_t)(mbase + r) * G_ + n] = f2b(acc[mt][nt][r] + bn);
        }
    }
}

// ---------------- LSTM recurrence over one T-chunk: one block per (b, dir).
// Thread map: j = tid>>2 (hidden unit), gq = tid&3 (gate i/f/g/o). The 4 gates
// of unit j are adjacent lanes of one wave -> exchange via __shfl, no gs[] LDS.
// hs ping-pong -> exactly ONE barrier per step. __launch_bounds__(512,2) keeps
// Wr[128] in arch VGPRs (cap 256) instead of AGPR round-trips.
__global__ __launch_bounds__(512, 2) void lstm_kernel(const u16* __restrict__ Whhc,
                                                      const u16* __restrict__ xwf,
                                                      const u16* __restrict__ xwb,
                                                      u16* __restrict__ hf,
                                                      u16* __restrict__ hb,
                                                      float* __restrict__ carry,
                                                      int TC, int t0f, int t0b, int first) {
    const int b = blockIdx.x;
    const int dir = blockIdx.y;
    const int tid = threadIdx.x;
    const int j = tid >> 2;
    const int gq = tid & 3;
    const int row = gq * H_ + j;                 // gate row in [0,512)
    const u16* W = Whhc + (size_t)dir * G_ * H_ + (size_t)row * H_;
    const u16* xw = (dir ? xwb : xwf) + (size_t)b * TC * G_ + row;
    u16* hout = (dir ? hb : hf) + (size_t)b * T_ * H_;
    const int t0 = dir ? t0b : t0f;
    const int ts = dir ? -1 : 1;
    float* carry_c = carry + (size_t)(dir * B_ + b) * H_;
    float* carry_h = carry + (size_t)(2 * B_ + dir * B_ + b) * H_;

    float Wr[H_];
#pragma unroll
    for (int k = 0; k < H_; k += 8) {
        uint4 v = *(const uint4*)(W + k);
        Wr[k + 0] = b2f((u16)(v.x & 0xffff)); Wr[k + 1] = b2f((u16)(v.x >> 16));
        Wr[k + 2] = b2f((u16)(v.y & 0xffff)); Wr[k + 3] = b2f((u16)(v.y >> 16));
        Wr[k + 4] = b2f((u16)(v.z & 0xffff)); Wr[k + 5] = b2f((u16)(v.z >> 16));
        Wr[k + 6] = b2f((u16)(v.w & 0xffff)); Wr[k + 7] = b2f((u16)(v.w >> 16));
    }

    __shared__ float hs[2][H_];
    float c = first ? 0.f : carry_c[j];          // replicated across the 4 gate lanes
    if (tid < H_) hs[0][tid] = first ? 0.f : carry_h[tid];
    __syncthreads();

    const int lane = tid & 63;
    const int lbase = lane & ~3;
    int cur = 0;
    float xv = b2f(xw[0]);                       // step-0 prefetch
    for (int r = 0; r < TC; ++r) {
        float xv_n = 0.f;
        if (r + 1 < TC) xv_n = b2f(xw[(size_t)(r + 1) * G_]);  // hide global latency
        const float* hsp = hs[cur];
        float a0 = 0.f, a1 = 0.f, a2 = 0.f, a3 = 0.f;
#pragma unroll
        for (int k = 0; k < H_; k += 4) {
            float4 hv = *(const float4*)&hsp[k];  // broadcast b128 LDS read
            a0 += Wr[k + 0] * hv.x;
            a1 += Wr[k + 1] * hv.y;
            a2 += Wr[k + 2] * hv.z;
            a3 += Wr[k + 3] * hv.w;
        }
        float g = xv + ((a0 + a1) + (a2 + a3));
        float v = (gq == 2) ? tanhf_(g) : sigmoidf_(g);
        float vi = __shfl(v, lbase + 0, 64);
        float vf = __shfl(v, lbase + 1, 64);
        float vg = __shfl(v, lbase + 2, 64);
        float vo = __shfl(v, lbase + 3, 64);
        c = vf * c + vi * vg;
        float h = vo * tanhf_(c);
        if (gq == 0) {
            hs[cur ^ 1][j] = h;
            int tg = t0 + ts * r;
            hout[(size_t)tg * H_ + j] = f2b(h);
        }
        __syncthreads();                          // single barrier per step
        cur ^= 1;
        xv = xv_n;
    }
    if (gq == 0) { carry_c[j] = c; carry_h[j] = hs[cur][j]; }
}

// ---------------- fc: logits = concat(hf,hb) @ fc_W^T + fc_b
__global__ __launch_bounds__(256) void fc_kernel(const u16* __restrict__ hf,
                                                 const u16* __restrict__ hb,
                                                 const u16* __restrict__ fcWc,
                                                 const float* __restrict__ fcbf,
                                                 const u32* __restrict__ flags,
                                                 float* __restrict__ logits,
                                                 void* __restrict__ dout) {
    __shared__ float Ws[C_ * 256];
    __shared__ float Hs[16 * 256];
    const int tid = threadIdx.x;
    const int bt0 = blockIdx.x * 64;
    const u32 isf32 = flags[0];
#pragma unroll
    for (int i = 0; i < C_; ++i) {
        int v = tid + i * 256;
        Ws[v] = b2f(fcWc[v]);
    }
    __syncthreads();
    for (int grp = 0; grp < 4; ++grp) {
        int btg = bt0 + grp * 16;
#pragma unroll
        for (int i = 0; i < 16; ++i) {
            int v = tid + i * 256;
            int r = v >> 8, k = v & 255;
            Hs[v] = (k < H_) ? b2f(hf[(size_t)(btg + r) * H_ + k])
                             : b2f(hb[(size_t)(btg + r) * H_ + (k - H_)]);
        }
        __syncthreads();
#pragma unroll
        for (int q = 0; q < 2; ++q) {
            int p = tid + q * 256;
            if (p < 16 * C_) {
                int r = p / C_, cc = p % C_;
                float acc = fcbf[cc];
                const float* wr = &Ws[cc * 256];
                const float* hr = &Hs[r * 256];
#pragma unroll
                for (int k = 0; k < 256; k += 4)
                    acc += wr[k] * hr[k] + wr[k + 1] * hr[k + 1] +
                           wr[k + 2] * hr[k + 2] + wr[k + 3] * hr[k + 3];
                size_t o = (size_t)(btg + r) * C_ + cc;
                logits[o] = acc;
                if (isf32) ((float*)dout)[1 + o] = acc;
                else       ((u16*)dout)[1 + o] = f2b(acc);
            }
        }
        __syncthreads();
    }
}

// ---------------- CRF phase A: per-(b,chunk) semiring product of step matrices.
__global__ __launch_bounds__(512) void crf_chunk(const float* __restrict__ logits,
                                                 const void* __restrict__ mask,
                                                 const float* __restrict__ transf,
                                                 const u32* __restrict__ flags,
                                                 float* __restrict__ Mc) {
    const int c = blockIdx.x;
    const int b = blockIdx.y;
    const int p = threadIdx.x;
    const bool act = p < C_ * C_;
    const int i = p / C_, j = p % C_;
    const u32 isbool = flags[1];

    __shared__ float P[C_ * C_];
    float trj[C_];
    if (act) {
#pragma unroll
        for (int k = 0; k < C_; ++k) trj[k] = transf[k * C_ + j];
        P[p] = (i == j) ? 0.f : -1e30f;
    }
    __syncthreads();

    const float* lg = logits + (size_t)b * T_ * C_;
    const int t0 = 1 + CS_ * c;

    float e = 0.f; int mk = 0;
    if (act) e = lg[(size_t)t0 * C_ + j];
    mk = loadmask(mask, b * T_ + t0, isbool);

    for (int s = 0; s < CS_; ++s) {
        int t = t0 + s;
        if (t >= T_) break;
        float e_n = 0.f; int mk_n = 0;
        int tn = t + 1;
        if (s + 1 < CS_ && tn < T_) {
            if (act) e_n = lg[(size_t)tn * C_ + j];
            mk_n = loadmask(mask, b * T_ + tn, isbool);
        }
        float nv = 0.f;
        if (act) {
            float sv[C_];
            float mx = -3e38f;
#pragma unroll
            for (int k = 0; k < C_; ++k) {
                sv[k] = P[i * C_ + k] + trj[k];
                mx = fmaxf(mx, sv[k]);
            }
            float sum = 0.f;
#pragma unroll
            for (int k = 0; k < C_; ++k) sum += __expf(sv[k] - mx);
            float la = mx + __logf(sum) + e;
            nv = mk ? la : P[p];
        }
        __syncthreads();
        if (act) P[p] = nv;
        __syncthreads();
        e = e_n; mk = mk_n;
    }
    if (act) Mc[((size_t)b * NCH_ + c) * (C_ * C_) + p] = P[p];
}

// ---------------- CRF phase B: per-b serial combine over 32 chunk matrices.
__global__ __launch_bounds__(64) void crf_combine(const float* __restrict__ logits,
                                                  const float* __restrict__ Mc,
                                                  float* __restrict__ log_den) {
    const int b = blockIdx.x;
    const int j = threadIdx.x;
    const bool act = j < C_;
    __shared__ float alpha[C_];
    const float* lg = logits + (size_t)b * T_ * C_;
    const float* mb = Mc + (size_t)b * NCH_ * (C_ * C_);
    if (act) alpha[j] = lg[j];
    __syncthreads();

    float mc[C_], mcn[C_];
    if (act) {
#pragma unroll
        for (int i = 0; i < C_; ++i) mc[i] = mb[i * C_ + j];
    }
    for (int c = 0; c < NCH_; ++c) {
        if (act && c + 1 < NCH_) {
#pragma unroll
            for (int i = 0; i < C_; ++i) mcn[i] = mb[(size_t)(c + 1) * (C_ * C_) + i * C_ + j];
        }
        float nv = 0.f;
        if (act) {
            float sv[C_];
            float mx = -3e38f;
#pragma unroll
            for (int i = 0; i < C_; ++i) {
                sv[i] = alpha[i] + mc[i];
                mx = fmaxf(mx, sv[i]);
            }
            float sum = 0.f;
#pragma unroll
            for (int i = 0; i < C_; ++i) sum += __expf(sv[i] - mx);
            nv = mx + __logf(sum);
        }
        __syncthreads();
        if (act) alpha[j] = nv;
        __syncthreads();
#pragma unroll
        for (int i = 0; i < C_; ++i) mc[i] = mcn[i];
    }
    if (j == 0) {
        float mx = -3e38f;
#pragma unroll
        for (int i = 0; i < C_; ++i) mx = fmaxf(mx, alpha[i]);
        float sum = 0.f;
#pragma unroll
        for (int i = 0; i < C_; ++i) sum += __expf(alpha[i] - mx);
        log_den[b] = mx + __logf(sum);
    }
}

// ---------------- loss numerator: one block per b, lane-strided over t
__global__ __launch_bounds__(64) void loss_partial(const float* __restrict__ logits,
                                                   const void* __restrict__ mask,
                                                   const int* __restrict__ tags,
                                                   const float* __restrict__ transf,
                                                   const u32* __restrict__ flags,
                                                   float* __restrict__ num) {
    const int b = blockIdx.x;
    const int lane = threadIdx.x;
    const u32 isbool = flags[1];
    const float* lg = logits + (size_t)b * T_ * C_;
    const int* tg = tags + b * T_;
    float s = 0.f;
    for (int t = lane; t < T_; t += 64) {
        int tt = tg[t];
        int mm = loadmask(mask, b * T_ + t, isbool);
        if (mm) s += lg[(size_t)t * C_ + tt];
        if (t >= 1) {
            int tp = tg[t - 1];
            int mp = loadmask(mask, b * T_ + t - 1, isbool);
            if (mm && mp) s += transf[tp * C_ + tt];
        }
    }
#pragma unroll
    for (int off = 32; off >= 1; off >>= 1)
        s += __shfl_down(s, off, 64);
    if (lane == 0) num[b] = s;
}

// ---------------- final: mean(log_den - log_num) -> dout[0]
__global__ __launch_bounds__(64) void loss_final(const float* __restrict__ den,
                                                 const float* __restrict__ num,
                                                 const u32* __restrict__ flags,
                                                 void* __restrict__ dout) {
    const int b = threadIdx.x;
    float v = den[b] - num[b];
#pragma unroll
    for (int off = 32; off >= 1; off >>= 1)
        v += __shfl_down(v, off, 64);
    if (b == 0) {
        float loss = v * (1.0f / B_);
        if (flags[0]) ((float*)dout)[0] = loss;
        else          ((u16*)dout)[0] = f2b(loss);
    }
}

extern "C" void kernel_launch(void* const* d_in, const int* in_sizes, int n_in,
                              void* d_out, int out_size, void* d_ws, size_t ws_size,
                              hipStream_t stream) {
    const int* x     = (const int*)d_in[0];
    const void* mask = d_in[1];
    const int* tags  = (const int*)d_in[2];
    const void* emb  = d_in[3];
    const void* Wihf = d_in[4];
    const void* Whhf = d_in[5];
    const void* bihf = d_in[6];
    const void* bhhf = d_in[7];
    const void* Wihb = d_in[8];
    const void* Whhb = d_in[9];
    const void* bihb = d_in[10];
    const void* bhhb = d_in[11];
    const void* fcW  = d_in[12];
    const void* fcb  = d_in[13];
    const void* trans= d_in[14];

    char* ws = (char*)d_ws;
    u32*   flags = (u32*)(ws + 0);                // 256
    u16*   Wpad  = (u16*)(ws + 256);              // 655,360
    u16*   Whhc  = (u16*)(ws + 655616);           // 262,144
    float* biasc = (float*)(ws + 917760);         // 4,096
    u16*   fcWc  = (u16*)(ws + 921856);           // 10,240
    float* fcbf  = (float*)(ws + 932096);         // 128
    float* transf= (float*)(ws + 932224);         // 1,664
    u16*   hf    = (u16*)(ws + 933888);           // 8,388,608
    u16*   hb    = (u16*)(ws + 9322496);          // 8,388,608
    float* lgf   = (float*)(ws + 17711104);       // 2,621,440
    float* den   = (float*)(ws + 20332544);       // 256
    float* carry = (float*)(ws + 20332800);       // 131,072
    float* Mc    = (float*)(ws + 20463872);       // 3,276,800
    float* numb  = (float*)(ws + 23740672);       // 256
    const size_t xw_off = 23740928;

    int TC, lg2;
    if (ws_size >= xw_off + 2ull * 65536ull * 128ull + 4096ull)      { TC = 128; lg2 = 7; }
    else if (ws_size >= xw_off + 2ull * 65536ull * 64ull + 4096ull)  { TC = 64;  lg2 = 6; }
    else                                                             { TC = 32;  lg2 = 5; }
    u16* xwf = (u16*)(ws + xw_off);
    u16* xwb = (u16*)(ws + xw_off + (size_t)65536 * TC);

    hipLaunchKernelGGL(sniff_kernel, dim3(1), dim3(64), 0, stream,
                       (const u32*)emb, (const u32*)mask, flags);
    hipLaunchKernelGGL(prep_kernel, dim3(1818), dim3(256), 0, stream,
                       Wihf, Wihb, Whhf, Whhb, bihf, bhhf, bihb, bhhb,
                       fcW, fcb, trans, flags, Wpad, Whhc, biasc, fcWc, fcbf, transf);

    const int nc = T_ / TC;
    for (int ci = 0; ci < nc; ++ci) {
        int t0f = ci * TC;
        int t0b = T_ - 1 - ci * TC;
        hipLaunchKernelGGL(gemm_xw, dim3((B_ * TC) / 128, 4, 2), dim3(256), 0, stream,
                           x, emb, Wpad, biasc, flags, xwf, xwb, lg2, t0f, t0b);
        hipLaunchKernelGGL(lstm_kernel, dim3(B_, 2), dim3(512), 0, stream,
                           Whhc, xwf, xwb, hf, hb, carry, TC, t0f, t0b, (ci == 0) ? 1 : 0);
    }

    hipLaunchKernelGGL(fc_kernel, dim3(512), dim3(256), 0, stream,
                       hf, hb, fcWc, fcbf, flags, lgf, d_out);
    hipLaunchKernelGGL(crf_chunk, dim3(NCH_, B_), dim3(512), 0, stream,
                       lgf, mask, transf, flags, Mc);
    hipLaunchKernelGGL(crf_combine, dim3(B_), dim3(64), 0, stream, lgf, Mc, den);
    hipLaunchKernelGGL(loss_partial, dim3(B_), dim3(64), 0, stream,
                       lgf, mask, tags, transf, flags, numb);
    hipLaunchKernelGGL(loss_final, dim3(1), dim3(64), 0, stream, den, numb, flags, d_out);
}

// Round 7
// 985.187 us; speedup vs baseline: 1.0332x; 1.0332x over previous
//
#include <hip/hip_runtime.h>
#include <hip/hip_bf16.h>

typedef unsigned short u16;
typedef unsigned char u8;
typedef unsigned int u32;
typedef __attribute__((ext_vector_type(8))) short short8;
typedef __attribute__((ext_vector_type(4))) float f32x4;

#define B_ 64
#define T_ 512
#define E_ 300
#define KP_ 320
#define H_ 128
#define G_ 512
#define C_ 20
#define NCH_ 32
#define CS_ 16

__device__ __forceinline__ float b2f(u16 u) {
    union { u32 i; float f; } v; v.i = ((u32)u) << 16; return v.f;
}
__device__ __forceinline__ u16 f2b(float f) {
    union { float f; u32 i; } v; v.f = f;
    u32 r = (v.i + 0x7fffu + ((v.i >> 16) & 1u)) >> 16;   // RNE
    return (u16)r;
}
__device__ __forceinline__ float loadf(const void* p, long i, u32 isf32) {
    return isf32 ? ((const float*)p)[i] : b2f(((const u16*)p)[i]);
}
__device__ __forceinline__ float sigmoidf_(float x) {
    return 1.0f / (1.0f + __expf(-x));
}
__device__ __forceinline__ float tanhf_(float x) {
    float cx = fminf(fmaxf(x, -15.f), 15.f);
    float e = __expf(2.f * cx);
    return (e - 1.f) / (e + 1.f);
}
__device__ __forceinline__ int loadmask(const void* m, int idx, u32 isbool) {
    return isbool ? (int)((const u8*)m)[idx] : ((const int*)m)[idx];
}

// ---------------- sniff input dtypes (deterministic, same result every call)
__global__ void sniff_kernel(const u32* __restrict__ emb32,
                             const u32* __restrict__ mask32,
                             u32* __restrict__ flags) {
    if (threadIdx.x == 0) {
        u32 nz = 0;
        for (int i = 150; i < 300; ++i) nz |= emb32[i];
        flags[0] = (nz == 0) ? 1u : 0u;          // f32 floats?
        u32 m0 = mask32[0];
        flags[1] = ((m0 & 0xFFFFFF00u) != 0) ? 1u : 0u;  // bool mask?
    }
}

// ---------------- prep: normalize weights into canonical buffers
__global__ __launch_bounds__(256) void prep_kernel(
    const void* __restrict__ Wihf, const void* __restrict__ Wihb,
    const void* __restrict__ Whhf, const void* __restrict__ Whhb,
    const void* __restrict__ bihf, const void* __restrict__ bhhf,
    const void* __restrict__ bihb, const void* __restrict__ bhhb,
    const void* __restrict__ fcW, const void* __restrict__ fcb,
    const void* __restrict__ trans, const u32* __restrict__ flags,
    u16* __restrict__ Wpad, u16* __restrict__ Whhc, float* __restrict__ biasc,
    u16* __restrict__ fcWc, float* __restrict__ fcbf, float* __restrict__ transf) {
    const u32 isf32 = flags[0];
    int idx = blockIdx.x * 256 + threadIdx.x;
    if (idx < 2 * G_ * KP_) {
        int dir = idx / (G_ * KP_), rem = idx % (G_ * KP_);
        int g = rem / KP_, kp = rem % KP_;
        const void* src = dir ? Wihb : Wihf;
        float v = (kp < E_) ? loadf(src, (long)g * E_ + kp, isf32) : 0.f;
        Wpad[idx] = f2b(v);
        return;
    }
    idx -= 2 * G_ * KP_;
    if (idx < 2 * G_ * H_) {
        int dir = idx >> 16, r = idx & 65535;
        Whhc[idx] = f2b(loadf(dir ? Whhb : Whhf, r, isf32));
        return;
    }
    idx -= 2 * G_ * H_;
    if (idx < 2 * G_) {
        int dir = idx >> 9, g = idx & 511;
        biasc[idx] = loadf(dir ? bihb : bihf, g, isf32) +
                     loadf(dir ? bhhb : bhhf, g, isf32);
        return;
    }
    idx -= 2 * G_;
    if (idx < C_ * 256) { fcWc[idx] = f2b(loadf(fcW, idx, isf32)); return; }
    idx -= C_ * 256;
    if (idx < C_) { fcbf[idx] = loadf(fcb, idx, isf32); return; }
    idx -= C_;
    if (idx < C_ * C_) { transf[idx] = loadf(trans, idx, isf32); return; }
}

// ---------------- chunked xw GEMM with fused embedding gather (dtype-adaptive A).
__global__ __launch_bounds__(256) void gemm_xw(const int* __restrict__ x,
                                               const void* __restrict__ emb,
                                               const u16* __restrict__ Wpad,
                                               const float* __restrict__ biasc,
                                               const u32* __restrict__ flags,
                                               u16* __restrict__ xwf, u16* __restrict__ xwb,
                                               int tclog2, int t0f, int t0b) {
    const int m0 = blockIdx.x * 128;
    const int n0 = blockIdx.y * 128;
    const int dir = blockIdx.z;
    const u16* Bw = Wpad + (size_t)dir * G_ * KP_;
    u16* out = dir ? xwb : xwf;
    const int t0 = dir ? t0b : t0f;
    const int ts = dir ? -1 : 1;
    const int tcm = (1 << tclog2) - 1;
    const u32 isf32 = flags[0];

    __shared__ __align__(16) short As[128 * 32];
    __shared__ __align__(16) short Bs[128 * 32];
    __shared__ int xs[128];

    const int tid = threadIdx.x;
    const int lane = tid & 63;
    const int wave = tid >> 6;
    const int wm = wave & 1, wn = wave >> 1;
    const int lr = lane & 15, lq = lane >> 4;

    if (tid < 128) {
        int i = m0 + tid;
        int b = i >> tclog2;
        int r = i & tcm;
        xs[tid] = x[b * T_ + t0 + ts * r];
    }
    __syncthreads();

    f32x4 acc[4][4];
#pragma unroll
    for (int mt = 0; mt < 4; ++mt)
#pragma unroll
        for (int nt = 0; nt < 4; ++nt)
            acc[mt][nt] = (f32x4){0.f, 0.f, 0.f, 0.f};

    for (int kb = 0; kb < KP_; kb += 32) {
        if (isf32) {
            const float* ef = (const float*)emb;
#pragma unroll
            for (int hh = 0; hh < 4; ++hh) {
                int c = tid + hh * 256;
                int row = c >> 3;
                int k4 = (c & 7) * 4;
                int k = kb + k4;
                uint2 o = make_uint2(0u, 0u);
                if (k < E_) {
                    float4 v = *(const float4*)(ef + (size_t)xs[row] * E_ + k);
                    o.x = (u32)f2b(v.x) | ((u32)f2b(v.y) << 16);
                    o.y = (u32)f2b(v.z) | ((u32)f2b(v.w) << 16);
                }
                *(uint2*)(&As[row * 32 + k4]) = o;
            }
        } else {
            const u16* eb = (const u16*)emb;
#pragma unroll
            for (int hh = 0; hh < 4; ++hh) {
                int c = tid + hh * 256;
                int row = c >> 3;
                int k4 = (c & 7) * 4;
                int k = kb + k4;
                uint2 va = make_uint2(0u, 0u);
                if (k < E_)
                    va = *(const uint2*)(eb + (size_t)xs[row] * E_ + k);
                *(uint2*)(&As[row * 32 + k4]) = va;
            }
        }
#pragma unroll
        for (int hh = 0; hh < 2; ++hh) {
            int c = tid + hh * 256;
            int row = c >> 2;
            int k8 = (c & 3) * 8;
            uint4 vb = *(const uint4*)(Bw + (size_t)(n0 + row) * KP_ + kb + k8);
            *(uint4*)(&Bs[row * 32 + k8]) = vb;
        }
        __syncthreads();
        short8 afr[4], bfr[4];
#pragma unroll
        for (int mt = 0; mt < 4; ++mt)
            afr[mt] = *(const short8*)&As[(wm * 64 + mt * 16 + lr) * 32 + lq * 8];
#pragma unroll
        for (int nt = 0; nt < 4; ++nt)
            bfr[nt] = *(const short8*)&Bs[(wn * 64 + nt * 16 + lr) * 32 + lq * 8];
#pragma unroll
        for (int mt = 0; mt < 4; ++mt)
#pragma unroll
            for (int nt = 0; nt < 4; ++nt)
                acc[mt][nt] = __builtin_amdgcn_mfma_f32_16x16x32_bf16(afr[mt], bfr[nt], acc[mt][nt], 0, 0, 0);
        __syncthreads();
    }
#pragma unroll
    for (int nt = 0; nt < 4; ++nt) {
        int n = n0 + wn * 64 + nt * 16 + lr;
        float bn = biasc[dir * G_ + n];
#pragma unroll
        for (int mt = 0; mt < 4; ++mt) {
            int mbase = m0 + wm * 64 + mt * 16 + lq * 4;
#pragma unroll
            for (int r = 0; r < 4; ++r)
                out[(size_t)(mbase + r) * G_ + n] = f2b(acc[mt][nt][r] + bn);
        }
    }
}

// ---------------- LSTM recurrence over one T-chunk: one block per (b, dir).
// ANTI-REMAT: W is staged global->LDS in 16.5KB chunks, each thread reads its
// row from LDS into Wr[128]; the same LDS is then REUSED for hs/gs, so the
// compiler cannot rematerialize Wr from memory -> it must live in registers.
__global__ __launch_bounds__(512, 1) void lstm_kernel(const u16* __restrict__ Whhc,
                                                      const u16* __restrict__ xwf,
                                                      const u16* __restrict__ xwb,
                                                      u16* __restrict__ hf,
                                                      u16* __restrict__ hb,
                                                      float* __restrict__ carry,
                                                      int TC, int t0f, int t0b, int first) {
    const int b = blockIdx.x;
    const int dir = blockIdx.y;
    const int tid = threadIdx.x;
    const u16* xw = (dir ? xwb : xwf) + (size_t)b * TC * G_ + tid;
    u16* hout = (dir ? hb : hf) + (size_t)b * T_ * H_;
    const int t0 = dir ? t0b : t0f;
    const int ts = dir ? -1 : 1;
    float* carry_c = carry + (size_t)(dir * B_ + b) * H_;
    float* carry_h = carry + (size_t)(2 * B_ + dir * B_ + b) * H_;

    __shared__ __align__(16) u32 smem[64 * 66];   // W staging; later hs/gs

    // ---- stage W through LDS (8 chunks of 64 rows), pull own row into regs
    const u32* Wg = (const u32*)(Whhc + (size_t)dir * G_ * H_);  // [512][64] u32
    float Wr[H_];
    for (int ch = 0; ch < 8; ++ch) {
        __syncthreads();
#pragma unroll
        for (int s = 0; s < 8; ++s) {
            int u = tid + s * 512;                 // 4096 u32 per chunk
            int row = u >> 6, col = u & 63;
            smem[row * 66 + col] = Wg[(size_t)(ch * 64 + row) * 64 + col];
        }
        __syncthreads();
        if ((tid >> 6) == ch) {
            int rr = tid & 63;
#pragma unroll
            for (int k = 0; k < 64; ++k) {
                u32 w = smem[rr * 66 + k];
                Wr[2 * k]     = b2f((u16)(w & 0xffff));
                Wr[2 * k + 1] = b2f((u16)(w >> 16));
            }
        }
    }
    __syncthreads();
    float* hs = (float*)smem;          // [128]  (overwrites staging -> pins Wr)
    float* gs = (float*)smem + 128;    // [512]

    float c0 = 0.f;
    if (tid < H_) {
        hs[tid] = first ? 0.f : carry_h[tid];
        c0 = first ? 0.f : carry_c[tid];
    }
    __syncthreads();

    const bool is_g = (tid >= 256) && (tid < 384);
    float xv = b2f(xw[0]);
    for (int r = 0; r < TC; ++r) {
        float xv_n = 0.f;
        if (r + 1 < TC) xv_n = b2f(xw[(size_t)(r + 1) * G_]);  // prefetch
        float a0 = 0.f, a1 = 0.f, a2 = 0.f, a3 = 0.f;
#pragma unroll
        for (int k = 0; k < H_; k += 4) {
            a0 += Wr[k]     * hs[k];
            a1 += Wr[k + 1] * hs[k + 1];
            a2 += Wr[k + 2] * hs[k + 2];
            a3 += Wr[k + 3] * hs[k + 3];
        }
        float g = xv + ((a0 + a1) + (a2 + a3));
        gs[tid] = is_g ? tanhf_(g) : sigmoidf_(g);
        __syncthreads();
        if (tid < H_) {
            float ig = gs[tid], fg = gs[H_ + tid], gg = gs[2 * H_ + tid], og = gs[3 * H_ + tid];
            c0 = fg * c0 + ig * gg;
            float h = og * tanhf_(c0);
            hs[tid] = h;
            hout[(size_t)(t0 + ts * r) * H_ + tid] = f2b(h);
        }
        __syncthreads();
        xv = xv_n;
    }
    if (tid < H_) { carry_c[tid] = c0; carry_h[tid] = hs[tid]; }
}

// ---------------- fc: logits = concat(hf,hb) @ fc_W^T + fc_b
__global__ __launch_bounds__(256) void fc_kernel(const u16* __restrict__ hf,
                                                 const u16* __restrict__ hb,
                                                 const u16* __restrict__ fcWc,
                                                 const float* __restrict__ fcbf,
                                                 const u32* __restrict__ flags,
                                                 float* __restrict__ logits,
                                                 void* __restrict__ dout) {
    __shared__ float Ws[C_ * 256];
    __shared__ float Hs[16 * 256];
    const int tid = threadIdx.x;
    const int bt0 = blockIdx.x * 64;
    const u32 isf32 = flags[0];
#pragma unroll
    for (int i = 0; i < C_; ++i) {
        int v = tid + i * 256;
        Ws[v] = b2f(fcWc[v]);
    }
    __syncthreads();
    for (int grp = 0; grp < 4; ++grp) {
        int btg = bt0 + grp * 16;
#pragma unroll
        for (int i = 0; i < 16; ++i) {
            int v = tid + i * 256;
            int r = v >> 8, k = v & 255;
            Hs[v] = (k < H_) ? b2f(hf[(size_t)(btg + r) * H_ + k])
                             : b2f(hb[(size_t)(btg + r) * H_ + (k - H_)]);
        }
        __syncthreads();
#pragma unroll
        for (int q = 0; q < 2; ++q) {
            int p = tid + q * 256;
            if (p < 16 * C_) {
                int r = p / C_, cc = p % C_;
                float acc = fcbf[cc];
                const float* wr = &Ws[cc * 256];
                const float* hr = &Hs[r * 256];
#pragma unroll
                for (int k = 0; k < 256; k += 4)
                    acc += wr[k] * hr[k] + wr[k + 1] * hr[k + 1] +
                           wr[k + 2] * hr[k + 2] + wr[k + 3] * hr[k + 3];
                size_t o = (size_t)(btg + r) * C_ + cc;
                logits[o] = acc;
                if (isf32) ((float*)dout)[1 + o] = acc;
                else       ((u16*)dout)[1 + o] = f2b(acc);
            }
        }
        __syncthreads();
    }
}

// ---------------- CRF phase A: per-(b,chunk) semiring product of step matrices.
__global__ __launch_bounds__(512) void crf_chunk(const float* __restrict__ logits,
                                                 const void* __restrict__ mask,
                                                 const float* __restrict__ transf,
                                                 const u32* __restrict__ flags,
                                                 float* __restrict__ Mc) {
    const int c = blockIdx.x;
    const int b = blockIdx.y;
    const int p = threadIdx.x;
    const bool act = p < C_ * C_;
    const int i = p / C_, j = p % C_;
    const u32 isbool = flags[1];

    __shared__ float P[C_ * C_];
    float trj[C_];
    if (act) {
#pragma unroll
        for (int k = 0; k < C_; ++k) trj[k] = transf[k * C_ + j];
        P[p] = (i == j) ? 0.f : -1e30f;
    }
    __syncthreads();

    const float* lg = logits + (size_t)b * T_ * C_;
    const int t0 = 1 + CS_ * c;

    float e = 0.f; int mk = 0;
    if (act) e = lg[(size_t)t0 * C_ + j];
    mk = loadmask(mask, b * T_ + t0, isbool);

    for (int s = 0; s < CS_; ++s) {
        int t = t0 + s;
        if (t >= T_) break;
        float e_n = 0.f; int mk_n = 0;
        int tn = t + 1;
        if (s + 1 < CS_ && tn < T_) {
            if (act) e_n = lg[(size_t)tn * C_ + j];
            mk_n = loadmask(mask, b * T_ + tn, isbool);
        }
        float nv = 0.f;
        if (act) {
            float sv[C_];
            float mx = -3e38f;
#pragma unroll
            for (int k = 0; k < C_; ++k) {
                sv[k] = P[i * C_ + k] + trj[k];
                mx = fmaxf(mx, sv[k]);
            }
            float sum = 0.f;
#pragma unroll
            for (int k = 0; k < C_; ++k) sum += __expf(sv[k] - mx);
            float la = mx + __logf(sum) + e;
            nv = mk ? la : P[p];
        }
        __syncthreads();
        if (act) P[p] = nv;
        __syncthreads();
        e = e_n; mk = mk_n;
    }
    if (act) Mc[((size_t)b * NCH_ + c) * (C_ * C_) + p] = P[p];
}

// ---------------- CRF phase B: per-b serial combine over 32 chunk matrices.
__global__ __launch_bounds__(64) void crf_combine(const float* __restrict__ logits,
                                                  const float* __restrict__ Mc,
                                                  float* __restrict__ log_den) {
    const int b = blockIdx.x;
    const int j = threadIdx.x;
    const bool act = j < C_;
    __shared__ float alpha[C_];
    const float* lg = logits + (size_t)b * T_ * C_;
    const float* mb = Mc + (size_t)b * NCH_ * (C_ * C_);
    if (act) alpha[j] = lg[j];
    __syncthreads();

    float mc[C_], mcn[C_];
    if (act) {
#pragma unroll
        for (int i = 0; i < C_; ++i) mc[i] = mb[i * C_ + j];
    }
    for (int c = 0; c < NCH_; ++c) {
        if (act && c + 1 < NCH_) {
#pragma unroll
            for (int i = 0; i < C_; ++i) mcn[i] = mb[(size_t)(c + 1) * (C_ * C_) + i * C_ + j];
        }
        float nv = 0.f;
        if (act) {
            float sv[C_];
            float mx = -3e38f;
#pragma unroll
            for (int i = 0; i < C_; ++i) {
                sv[i] = alpha[i] + mc[i];
                mx = fmaxf(mx, sv[i]);
            }
            float sum = 0.f;
#pragma unroll
            for (int i = 0; i < C_; ++i) sum += __expf(sv[i] - mx);
            nv = mx + __logf(sum);
        }
        __syncthreads();
        if (act) alpha[j] = nv;
        __syncthreads();
#pragma unroll
        for (int i = 0; i < C_; ++i) mc[i] = mcn[i];
    }
    if (j == 0) {
        float mx = -3e38f;
#pragma unroll
        for (int i = 0; i < C_; ++i) mx = fmaxf(mx, alpha[i]);
        float sum = 0.f;
#pragma unroll
        for (int i = 0; i < C_; ++i) sum += __expf(alpha[i] - mx);
        log_den[b] = mx + __logf(sum);
    }
}

// ---------------- loss numerator: one block per b, lane-strided over t
__global__ __launch_bounds__(64) void loss_partial(const float* __restrict__ logits,
                                                   const void* __restrict__ mask,
                                                   const int* __restrict__ tags,
                                                   const float* __restrict__ transf,
                                                   const u32* __restrict__ flags,
                                                   float* __restrict__ num) {
    const int b = blockIdx.x;
    const int lane = threadIdx.x;
    const u32 isbool = flags[1];
    const float* lg = logits + (size_t)b * T_ * C_;
    const int* tg = tags + b * T_;
    float s = 0.f;
    for (int t = lane; t < T_; t += 64) {
        int tt = tg[t];
        int mm = loadmask(mask, b * T_ + t, isbool);
        if (mm) s += lg[(size_t)t * C_ + tt];
        if (t >= 1) {
            int tp = tg[t - 1];
            int mp = loadmask(mask, b * T_ + t - 1, isbool);
            if (mm && mp) s += transf[tp * C_ + tt];
        }
    }
#pragma unroll
    for (int off = 32; off >= 1; off >>= 1)
        s += __shfl_down(s, off, 64);
    if (lane == 0) num[b] = s;
}

// ---------------- final: mean(log_den - log_num) -> dout[0]
__global__ __launch_bounds__(64) void loss_final(const float* __restrict__ den,
                                                 const float* __restrict__ num,
                                                 const u32* __restrict__ flags,
                                                 void* __restrict__ dout) {
    const int b = threadIdx.x;
    float v = den[b] - num[b];
#pragma unroll
    for (int off = 32; off >= 1; off >>= 1)
        v += __shfl_down(v, off, 64);
    if (b == 0) {
        float loss = v * (1.0f / B_);
        if (flags[0]) ((float*)dout)[0] = loss;
        else          ((u16*)dout)[0] = f2b(loss);
    }
}

extern "C" void kernel_launch(void* const* d_in, const int* in_sizes, int n_in,
                              void* d_out, int out_size, void* d_ws, size_t ws_size,
                              hipStream_t stream) {
    const int* x     = (const int*)d_in[0];
    const void* mask = d_in[1];
    const int* tags  = (const int*)d_in[2];
    const void* emb  = d_in[3];
    const void* Wihf = d_in[4];
    const void* Whhf = d_in[5];
    const void* bihf = d_in[6];
    const void* bhhf = d_in[7];
    const void* Wihb = d_in[8];
    const void* Whhb = d_in[9];
    const void* bihb = d_in[10];
    const void* bhhb = d_in[11];
    const void* fcW  = d_in[12];
    const void* fcb  = d_in[13];
    const void* trans= d_in[14];

    char* ws = (char*)d_ws;
    u32*   flags = (u32*)(ws + 0);                // 256
    u16*   Wpad  = (u16*)(ws + 256);              // 655,360
    u16*   Whhc  = (u16*)(ws + 655616);           // 262,144
    float* biasc = (float*)(ws + 917760);         // 4,096
    u16*   fcWc  = (u16*)(ws + 921856);           // 10,240
    float* fcbf  = (float*)(ws + 932096);         // 128
    float* transf= (float*)(ws + 932224);         // 1,664
    u16*   hf    = (u16*)(ws + 933888);           // 8,388,608
    u16*   hb    = (u16*)(ws + 9322496);          // 8,388,608
    float* lgf   = (float*)(ws + 17711104);       // 2,621,440
    float* den   = (float*)(ws + 20332544);       // 256
    float* carry = (float*)(ws + 20332800);       // 131,072
    float* Mc    = (float*)(ws + 20463872);       // 3,276,800
    float* numb  = (float*)(ws + 23740672);       // 256
    const size_t xw_off = 23740928;

    int TC, lg2;
    if (ws_size >= xw_off + 2ull * 65536ull * 512ull + 4096ull)      { TC = 512; lg2 = 9; }
    else if (ws_size >= xw_off + 2ull * 65536ull * 256ull + 4096ull) { TC = 256; lg2 = 8; }
    else if (ws_size >= xw_off + 2ull * 65536ull * 128ull + 4096ull) { TC = 128; lg2 = 7; }
    else if (ws_size >= xw_off + 2ull * 65536ull * 64ull + 4096ull)  { TC = 64;  lg2 = 6; }
    else                                                             { TC = 32;  lg2 = 5; }
    u16* xwf = (u16*)(ws + xw_off);
    u16* xwb = (u16*)(ws + xw_off + (size_t)65536 * TC);

    hipLaunchKernelGGL(sniff_kernel, dim3(1), dim3(64), 0, stream,
                       (const u32*)emb, (const u32*)mask, flags);
    hipLaunchKernelGGL(prep_kernel, dim3(1818), dim3(256), 0, stream,
                       Wihf, Wihb, Whhf, Whhb, bihf, bhhf, bihb, bhhb,
                       fcW, fcb, trans, flags, Wpad, Whhc, biasc, fcWc, fcbf, transf);

    const int nc = T_ / TC;
    for (int ci = 0; ci < nc; ++ci) {
        int t0f = ci * TC;
        int t0b = T_ - 1 - ci * TC;
        hipLaunchKernelGGL(gemm_xw, dim3((B_ * TC) / 128, 4, 2), dim3(256), 0, stream,
                           x, emb, Wpad, biasc, flags, xwf, xwb, lg2, t0f, t0b);
        hipLaunchKernelGGL(lstm_kernel, dim3(B_, 2), dim3(512), 0, stream,
                           Whhc, xwf, xwb, hf, hb, carry, TC, t0f, t0b, (ci == 0) ? 1 : 0);
    }

    hipLaunchKernelGGL(fc_kernel, dim3(512), dim3(256), 0, stream,
                       hf, hb, fcWc, fcbf, flags, lgf, d_out);
    hipLaunchKernelGGL(crf_chunk, dim3(NCH_, B_), dim3(512), 0, stream,
                       lgf, mask, transf, flags, Mc);
    hipLaunchKernelGGL(crf_combine, dim3(B_), dim3(64), 0, stream, lgf, Mc, den);
    hipLaunchKernelGGL(loss_partial, dim3(B_), dim3(64), 0, stream,
                       lgf, mask, tags, transf, flags, numb);
    hipLaunchKernelGGL(loss_final, dim3(1), dim3(64), 0, stream, den, numb, flags, d_out);
}

// Round 8
// 880.125 us; speedup vs baseline: 1.1565x; 1.1194x over previous
//
#include <hip/hip_runtime.h>
#include <hip/hip_bf16.h>
#include <hip/hip_fp16.h>

typedef unsigned short u16;
typedef unsigned char u8;
typedef unsigned int u32;
typedef __attribute__((ext_vector_type(8))) short short8;
typedef __attribute__((ext_vector_type(4))) float f32x4;
typedef __attribute__((ext_vector_type(2))) _Float16 half2_t;

#define B_ 64
#define T_ 512
#define E_ 300
#define KP_ 320
#define H_ 128
#define G_ 512
#define C_ 20
#define NCH_ 32
#define CS_ 16

__device__ __forceinline__ float b2f(u16 u) {
    union { u32 i; float f; } v; v.i = ((u32)u) << 16; return v.f;
}
__device__ __forceinline__ u16 f2b(float f) {
    union { float f; u32 i; } v; v.f = f;
    u32 r = (v.i + 0x7fffu + ((v.i >> 16) & 1u)) >> 16;   // RNE
    return (u16)r;
}
__device__ __forceinline__ float loadf(const void* p, long i, u32 isf32) {
    return isf32 ? ((const float*)p)[i] : b2f(((const u16*)p)[i]);
}
__device__ __forceinline__ float sigmoidf_(float x) {
    return 1.0f / (1.0f + __expf(-x));
}
__device__ __forceinline__ float tanhf_(float x) {
    float cx = fminf(fmaxf(x, -15.f), 15.f);
    float e = __expf(2.f * cx);
    return (e - 1.f) / (e + 1.f);
}
__device__ __forceinline__ int loadmask(const void* m, int idx, u32 isbool) {
    return isbool ? (int)((const u8*)m)[idx] : ((const int*)m)[idx];
}
__device__ __forceinline__ u16 f2h(float f) {
    __half h = __float2half(f);
    return __half_as_ushort(h);
}
// packed f16x2 dot-accumulate: a.x*b.x + a.y*b.y + c (one v_dot2 inst)
__device__ __forceinline__ float dot2f(u32 a, u32 b, float c) {
#if __has_builtin(__builtin_amdgcn_fdot2)
    return __builtin_amdgcn_fdot2(__builtin_bit_cast(half2_t, a),
                                  __builtin_bit_cast(half2_t, b), c, false);
#else
    half2_t av = __builtin_bit_cast(half2_t, a);
    half2_t bv = __builtin_bit_cast(half2_t, b);
    return c + (float)av.x * (float)bv.x + (float)av.y * (float)bv.y;
#endif
}

// ---------------- sniff input dtypes (deterministic, same result every call)
__global__ void sniff_kernel(const u32* __restrict__ emb32,
                             const u32* __restrict__ mask32,
                             u32* __restrict__ flags) {
    if (threadIdx.x == 0) {
        u32 nz = 0;
        for (int i = 150; i < 300; ++i) nz |= emb32[i];
        flags[0] = (nz == 0) ? 1u : 0u;          // f32 floats?
        u32 m0 = mask32[0];
        flags[1] = ((m0 & 0xFFFFFF00u) != 0) ? 1u : 0u;  // bool mask?
    }
}

// ---------------- prep: normalize weights into canonical buffers
// Wpad bf16 [2][512][320]; Whh2 u32(f16x2) [2][512][64]; biasc f32 [2][512];
// fcWc bf16 [20][256]; fcbf f32 [20]; transf f32 [20][20]
__global__ __launch_bounds__(256) void prep_kernel(
    const void* __restrict__ Wihf, const void* __restrict__ Wihb,
    const void* __restrict__ Whhf, const void* __restrict__ Whhb,
    const void* __restrict__ bihf, const void* __restrict__ bhhf,
    const void* __restrict__ bihb, const void* __restrict__ bhhb,
    const void* __restrict__ fcW, const void* __restrict__ fcb,
    const void* __restrict__ trans, const u32* __restrict__ flags,
    u16* __restrict__ Wpad, u32* __restrict__ Whh2, float* __restrict__ biasc,
    u16* __restrict__ fcWc, float* __restrict__ fcbf, float* __restrict__ transf) {
    const u32 isf32 = flags[0];
    int idx = blockIdx.x * 256 + threadIdx.x;
    if (idx < 2 * G_ * KP_) {                    // 327680
        int dir = idx / (G_ * KP_), rem = idx % (G_ * KP_);
        int g = rem / KP_, kp = rem % KP_;
        const void* src = dir ? Wihb : Wihf;
        float v = (kp < E_) ? loadf(src, (long)g * E_ + kp, isf32) : 0.f;
        Wpad[idx] = f2b(v);
        return;
    }
    idx -= 2 * G_ * KP_;
    if (idx < 2 * G_ * 64) {                     // 65536 packed u32
        int dir = idx >> 15, rem = idx & 32767;
        int row = rem >> 6, k2 = rem & 63;
        const void* src = dir ? Whhb : Whhf;
        float w0 = loadf(src, (long)row * H_ + 2 * k2, isf32);
        float w1 = loadf(src, (long)row * H_ + 2 * k2 + 1, isf32);
        Whh2[idx] = (u32)f2h(w0) | ((u32)f2h(w1) << 16);
        return;
    }
    idx -= 2 * G_ * 64;
    if (idx < 2 * G_) {                          // 1024
        int dir = idx >> 9, g = idx & 511;
        biasc[idx] = loadf(dir ? bihb : bihf, g, isf32) +
                     loadf(dir ? bhhb : bhhf, g, isf32);
        return;
    }
    idx -= 2 * G_;
    if (idx < C_ * 256) { fcWc[idx] = f2b(loadf(fcW, idx, isf32)); return; }
    idx -= C_ * 256;
    if (idx < C_) { fcbf[idx] = loadf(fcb, idx, isf32); return; }
    idx -= C_;
    if (idx < C_ * C_) { transf[idx] = loadf(trans, idx, isf32); return; }
}

// ---------------- chunked xw GEMM with fused embedding gather (dtype-adaptive A).
__global__ __launch_bounds__(256) void gemm_xw(const int* __restrict__ x,
                                               const void* __restrict__ emb,
                                               const u16* __restrict__ Wpad,
                                               const float* __restrict__ biasc,
                                               const u32* __restrict__ flags,
                                               u16* __restrict__ xwf, u16* __restrict__ xwb,
                                               int tclog2, int t0f, int t0b) {
    const int m0 = blockIdx.x * 128;
    const int n0 = blockIdx.y * 128;
    const int dir = blockIdx.z;
    const u16* Bw = Wpad + (size_t)dir * G_ * KP_;
    u16* out = dir ? xwb : xwf;
    const int t0 = dir ? t0b : t0f;
    const int ts = dir ? -1 : 1;
    const int tcm = (1 << tclog2) - 1;
    const u32 isf32 = flags[0];

    __shared__ __align__(16) short As[128 * 32];
    __shared__ __align__(16) short Bs[128 * 32];
    __shared__ int xs[128];

    const int tid = threadIdx.x;
    const int lane = tid & 63;
    const int wave = tid >> 6;
    const int wm = wave & 1, wn = wave >> 1;
    const int lr = lane & 15, lq = lane >> 4;

    if (tid < 128) {
        int i = m0 + tid;
        int b = i >> tclog2;
        int r = i & tcm;
        xs[tid] = x[b * T_ + t0 + ts * r];
    }
    __syncthreads();

    f32x4 acc[4][4];
#pragma unroll
    for (int mt = 0; mt < 4; ++mt)
#pragma unroll
        for (int nt = 0; nt < 4; ++nt)
            acc[mt][nt] = (f32x4){0.f, 0.f, 0.f, 0.f};

    for (int kb = 0; kb < KP_; kb += 32) {
        if (isf32) {
            const float* ef = (const float*)emb;
#pragma unroll
            for (int hh = 0; hh < 4; ++hh) {
                int c = tid + hh * 256;
                int row = c >> 3;
                int k4 = (c & 7) * 4;
                int k = kb + k4;
                uint2 o = make_uint2(0u, 0u);
                if (k < E_) {
                    float4 v = *(const float4*)(ef + (size_t)xs[row] * E_ + k);
                    o.x = (u32)f2b(v.x) | ((u32)f2b(v.y) << 16);
                    o.y = (u32)f2b(v.z) | ((u32)f2b(v.w) << 16);
                }
                *(uint2*)(&As[row * 32 + k4]) = o;
            }
        } else {
            const u16* eb = (const u16*)emb;
#pragma unroll
            for (int hh = 0; hh < 4; ++hh) {
                int c = tid + hh * 256;
                int row = c >> 3;
                int k4 = (c & 7) * 4;
                int k = kb + k4;
                uint2 va = make_uint2(0u, 0u);
                if (k < E_)
                    va = *(const uint2*)(eb + (size_t)xs[row] * E_ + k);
                *(uint2*)(&As[row * 32 + k4]) = va;
            }
        }
#pragma unroll
        for (int hh = 0; hh < 2; ++hh) {
            int c = tid + hh * 256;
            int row = c >> 2;
            int k8 = (c & 3) * 8;
            uint4 vb = *(const uint4*)(Bw + (size_t)(n0 + row) * KP_ + kb + k8);
            *(uint4*)(&Bs[row * 32 + k8]) = vb;
        }
        __syncthreads();
        short8 afr[4], bfr[4];
#pragma unroll
        for (int mt = 0; mt < 4; ++mt)
            afr[mt] = *(const short8*)&As[(wm * 64 + mt * 16 + lr) * 32 + lq * 8];
#pragma unroll
        for (int nt = 0; nt < 4; ++nt)
            bfr[nt] = *(const short8*)&Bs[(wn * 64 + nt * 16 + lr) * 32 + lq * 8];
#pragma unroll
        for (int mt = 0; mt < 4; ++mt)
#pragma unroll
            for (int nt = 0; nt < 4; ++nt)
                acc[mt][nt] = __builtin_amdgcn_mfma_f32_16x16x32_bf16(afr[mt], bfr[nt], acc[mt][nt], 0, 0, 0);
        __syncthreads();
    }
#pragma unroll
    for (int nt = 0; nt < 4; ++nt) {
        int n = n0 + wn * 64 + nt * 16 + lr;
        float bn = biasc[dir * G_ + n];
#pragma unroll
        for (int mt = 0; mt < 4; ++mt) {
            int mbase = m0 + wm * 64 + mt * 16 + lq * 4;
#pragma unroll
            for (int r = 0; r < 4; ++r)
                out[(size_t)(mbase + r) * G_ + n] = f2b(acc[mt][nt][r] + bn);
        }
    }
}

// ---------------- LSTM recurrence: one block per (b, dir), 512 threads.
// j = tid>>2 (unit), gq = tid&3 (gate). W row held in 16 NAMED uint4 vars
// (f16x2 packed, 64 VGPRs, no alloca -> cannot be demoted to scratch).
// h as packed f16 in LDS (2x256B ping-pong), 16 broadcast b128 reads/step.
// Gate exchange via quad shuffles; ONE barrier per step.
#define DOTQ(wq, hq) \
    acc = dot2f(wq.x, hq.x, acc); acc = dot2f(wq.y, hq.y, acc); \
    acc = dot2f(wq.z, hq.z, acc); acc = dot2f(wq.w, hq.w, acc);

__global__ __launch_bounds__(512, 1) void lstm_kernel(const u32* __restrict__ Whh2,
                                                      const u16* __restrict__ xwf,
                                                      const u16* __restrict__ xwb,
                                                      u16* __restrict__ hf,
                                                      u16* __restrict__ hb,
                                                      float* __restrict__ carry,
                                                      int TC, int t0f, int t0b, int first) {
    const int b = blockIdx.x;
    const int dir = blockIdx.y;
    const int tid = threadIdx.x;
    const int j = tid >> 2;
    const int gq = tid & 3;
    const int row = gq * H_ + j;
    const u16* xw = (dir ? xwb : xwf) + (size_t)b * TC * G_ + row;
    u16* hout = (dir ? hb : hf) + (size_t)b * T_ * H_;
    const int t0 = dir ? t0b : t0f;
    const int ts = dir ? -1 : 1;
    float* carry_c = carry + (size_t)(dir * B_ + b) * H_;
    float* carry_h = carry + (size_t)(2 * B_ + dir * B_ + b) * H_;

    const uint4* W4 = (const uint4*)(Whh2 + (size_t)dir * G_ * 64 + (size_t)row * 64);
    uint4 w0 = W4[0],  w1 = W4[1],  w2 = W4[2],  w3 = W4[3];
    uint4 w4 = W4[4],  w5 = W4[5],  w6 = W4[6],  w7 = W4[7];
    uint4 w8 = W4[8],  w9 = W4[9],  w10 = W4[10], w11 = W4[11];
    uint4 w12 = W4[12], w13 = W4[13], w14 = W4[14], w15 = W4[15];

    __shared__ __align__(16) u32 hs2[2][64];     // h packed f16x2

    float c0 = first ? 0.f : carry_c[j];
    if (tid < 64) {
        float ha = first ? 0.f : carry_h[2 * tid];
        float hb2 = first ? 0.f : carry_h[2 * tid + 1];
        hs2[0][tid] = (u32)f2h(ha) | ((u32)f2h(hb2) << 16);
    }
    __syncthreads();

    const int lane = tid & 63;
    const int lbase = lane & ~3;
    int cur = 0;
    float xv = b2f(xw[0]);
    float hlast = 0.f;
    for (int r = 0; r < TC; ++r) {
        float xv_n = 0.f;
        if (r + 1 < TC) xv_n = b2f(xw[(size_t)(r + 1) * G_]);
        const uint4* hp = (const uint4*)hs2[cur];
        float acc = 0.f;
        { uint4 hq = hp[0];  DOTQ(w0, hq) }
        { uint4 hq = hp[1];  DOTQ(w1, hq) }
        { uint4 hq = hp[2];  DOTQ(w2, hq) }
        { uint4 hq = hp[3];  DOTQ(w3, hq) }
        { uint4 hq = hp[4];  DOTQ(w4, hq) }
        { uint4 hq = hp[5];  DOTQ(w5, hq) }
        { uint4 hq = hp[6];  DOTQ(w6, hq) }
        { uint4 hq = hp[7];  DOTQ(w7, hq) }
        { uint4 hq = hp[8];  DOTQ(w8, hq) }
        { uint4 hq = hp[9];  DOTQ(w9, hq) }
        { uint4 hq = hp[10]; DOTQ(w10, hq) }
        { uint4 hq = hp[11]; DOTQ(w11, hq) }
        { uint4 hq = hp[12]; DOTQ(w12, hq) }
        { uint4 hq = hp[13]; DOTQ(w13, hq) }
        { uint4 hq = hp[14]; DOTQ(w14, hq) }
        { uint4 hq = hp[15]; DOTQ(w15, hq) }
        float g = xv + acc;
        float v = (gq == 2) ? tanhf_(g) : sigmoidf_(g);
        float vi = __shfl(v, lbase + 0, 64);
        float vf = __shfl(v, lbase + 1, 64);
        float vg = __shfl(v, lbase + 2, 64);
        float vo = __shfl(v, lbase + 3, 64);
        c0 = vf * c0 + vi * vg;
        float h = vo * tanhf_(c0);
        hlast = h;
        float hnxt = __shfl(h, lane + 4, 64);     // h of unit j+1 (same wave)
        if (gq == 0) {
            hout[(size_t)(t0 + ts * r) * H_ + j] = f2b(h);
            if ((j & 1) == 0)
                hs2[cur ^ 1][j >> 1] = (u32)f2h(h) | ((u32)f2h(hnxt) << 16);
        }
        __syncthreads();
        cur ^= 1;
        xv = xv_n;
    }
    if (gq == 0) { carry_c[j] = c0; carry_h[j] = hlast; }
}

// ---------------- fc: logits = concat(hf,hb) @ fc_W^T + fc_b
__global__ __launch_bounds__(256) void fc_kernel(const u16* __restrict__ hf,
                                                 const u16* __restrict__ hb,
                                                 const u16* __restrict__ fcWc,
                                                 const float* __restrict__ fcbf,
                                                 const u32* __restrict__ flags,
                                                 float* __restrict__ logits,
                                                 void* __restrict__ dout) {
    __shared__ float Ws[C_ * 256];
    __shared__ float Hs[16 * 256];
    const int tid = threadIdx.x;
    const int bt0 = blockIdx.x * 64;
    const u32 isf32 = flags[0];
#pragma unroll
    for (int i = 0; i < C_; ++i) {
        int v = tid + i * 256;
        Ws[v] = b2f(fcWc[v]);
    }
    __syncthreads();
    for (int grp = 0; grp < 4; ++grp) {
        int btg = bt0 + grp * 16;
#pragma unroll
        for (int i = 0; i < 16; ++i) {
            int v = tid + i * 256;
            int r = v >> 8, k = v & 255;
            Hs[v] = (k < H_) ? b2f(hf[(size_t)(btg + r) * H_ + k])
                             : b2f(hb[(size_t)(btg + r) * H_ + (k - H_)]);
        }
        __syncthreads();
#pragma unroll
        for (int q = 0; q < 2; ++q) {
            int p = tid + q * 256;
            if (p < 16 * C_) {
                int r = p / C_, cc = p % C_;
                float acc = fcbf[cc];
                const float* wr = &Ws[cc * 256];
                const float* hr = &Hs[r * 256];
#pragma unroll
                for (int k = 0; k < 256; k += 4)
                    acc += wr[k] * hr[k] + wr[k + 1] * hr[k + 1] +
                           wr[k + 2] * hr[k + 2] + wr[k + 3] * hr[k + 3];
                size_t o = (size_t)(btg + r) * C_ + cc;
                logits[o] = acc;
                if (isf32) ((float*)dout)[1 + o] = acc;
                else       ((u16*)dout)[1 + o] = f2b(acc);
            }
        }
        __syncthreads();
    }
}

// ---------------- CRF phase A: per-(b,chunk) semiring product of step matrices.
__global__ __launch_bounds__(512) void crf_chunk(const float* __restrict__ logits,
                                                 const void* __restrict__ mask,
                                                 const float* __restrict__ transf,
                                                 const u32* __restrict__ flags,
                                                 float* __restrict__ Mc) {
    const int c = blockIdx.x;
    const int b = blockIdx.y;
    const int p = threadIdx.x;
    const bool act = p < C_ * C_;
    const int i = p / C_, j = p % C_;
    const u32 isbool = flags[1];

    __shared__ float P[C_ * C_];
    float trj[C_];
    if (act) {
#pragma unroll
        for (int k = 0; k < C_; ++k) trj[k] = transf[k * C_ + j];
        P[p] = (i == j) ? 0.f : -1e30f;
    }
    __syncthreads();

    const float* lg = logits + (size_t)b * T_ * C_;
    const int t0 = 1 + CS_ * c;

    float e = 0.f; int mk = 0;
    if (act) e = lg[(size_t)t0 * C_ + j];
    mk = loadmask(mask, b * T_ + t0, isbool);

    for (int s = 0; s < CS_; ++s) {
        int t = t0 + s;
        if (t >= T_) break;
        float e_n = 0.f; int mk_n = 0;
        int tn = t + 1;
        if (s + 1 < CS_ && tn < T_) {
            if (act) e_n = lg[(size_t)tn * C_ + j];
            mk_n = loadmask(mask, b * T_ + tn, isbool);
        }
        float nv = 0.f;
        if (act) {
            float sv[C_];
            float mx = -3e38f;
#pragma unroll
            for (int k = 0; k < C_; ++k) {
                sv[k] = P[i * C_ + k] + trj[k];
                mx = fmaxf(mx, sv[k]);
            }
            float sum = 0.f;
#pragma unroll
            for (int k = 0; k < C_; ++k) sum += __expf(sv[k] - mx);
            float la = mx + __logf(sum) + e;
            nv = mk ? la : P[p];
        }
        __syncthreads();
        if (act) P[p] = nv;
        __syncthreads();
        e = e_n; mk = mk_n;
    }
    if (act) Mc[((size_t)b * NCH_ + c) * (C_ * C_) + p] = P[p];
}

// ---------------- CRF phase B: per-b serial combine over 32 chunk matrices.
__global__ __launch_bounds__(64) void crf_combine(const float* __restrict__ logits,
                                                  const float* __restrict__ Mc,
                                                  float* __restrict__ log_den) {
    const int b = blockIdx.x;
    const int j = threadIdx.x;
    const bool act = j < C_;
    __shared__ float alpha[C_];
    const float* lg = logits + (size_t)b * T_ * C_;
    const float* mb = Mc + (size_t)b * NCH_ * (C_ * C_);
    if (act) alpha[j] = lg[j];
    __syncthreads();

    float mc[C_], mcn[C_];
    if (act) {
#pragma unroll
        for (int i = 0; i < C_; ++i) mc[i] = mb[i * C_ + j];
    }
    for (int c = 0; c < NCH_; ++c) {
        if (act && c + 1 < NCH_) {
#pragma unroll
            for (int i = 0; i < C_; ++i) mcn[i] = mb[(size_t)(c + 1) * (C_ * C_) + i * C_ + j];
        }
        float nv = 0.f;
        if (act) {
            float sv[C_];
            float mx = -3e38f;
#pragma unroll
            for (int i = 0; i < C_; ++i) {
                sv[i] = alpha[i] + mc[i];
                mx = fmaxf(mx, sv[i]);
            }
            float sum = 0.f;
#pragma unroll
            for (int i = 0; i < C_; ++i) sum += __expf(sv[i] - mx);
            nv = mx + __logf(sum);
        }
        __syncthreads();
        if (act) alpha[j] = nv;
        __syncthreads();
#pragma unroll
        for (int i = 0; i < C_; ++i) mc[i] = mcn[i];
    }
    if (j == 0) {
        float mx = -3e38f;
#pragma unroll
        for (int i = 0; i < C_; ++i) mx = fmaxf(mx, alpha[i]);
        float sum = 0.f;
#pragma unroll
        for (int i = 0; i < C_; ++i) sum += __expf(alpha[i] - mx);
        log_den[b] = mx + __logf(sum);
    }
}

// ---------------- loss numerator: one block per b, lane-strided over t
__global__ __launch_bounds__(64) void loss_partial(const float* __restrict__ logits,
                                                   const void* __restrict__ mask,
                                                   const int* __restrict__ tags,
                                                   const float* __restrict__ transf,
                                                   const u32* __restrict__ flags,
                                                   float* __restrict__ num) {
    const int b = blockIdx.x;
    const int lane = threadIdx.x;
    const u32 isbool = flags[1];
    const float* lg = logits + (size_t)b * T_ * C_;
    const int* tg = tags + b * T_;
    float s = 0.f;
    for (int t = lane; t < T_; t += 64) {
        int tt = tg[t];
        int mm = loadmask(mask, b * T_ + t, isbool);
        if (mm) s += lg[(size_t)t * C_ + tt];
        if (t >= 1) {
            int tp = tg[t - 1];
            int mp = loadmask(mask, b * T_ + t - 1, isbool);
            if (mm && mp) s += transf[tp * C_ + tt];
        }
    }
#pragma unroll
    for (int off = 32; off >= 1; off >>= 1)
        s += __shfl_down(s, off, 64);
    if (lane == 0) num[b] = s;
}

// ---------------- final: mean(log_den - log_num) -> dout[0]
__global__ __launch_bounds__(64) void loss_final(const float* __restrict__ den,
                                                 const float* __restrict__ num,
                                                 const u32* __restrict__ flags,
                                                 void* __restrict__ dout) {
    const int b = threadIdx.x;
    float v = den[b] - num[b];
#pragma unroll
    for (int off = 32; off >= 1; off >>= 1)
        v += __shfl_down(v, off, 64);
    if (b == 0) {
        float loss = v * (1.0f / B_);
        if (flags[0]) ((float*)dout)[0] = loss;
        else          ((u16*)dout)[0] = f2b(loss);
    }
}

extern "C" void kernel_launch(void* const* d_in, const int* in_sizes, int n_in,
                              void* d_out, int out_size, void* d_ws, size_t ws_size,
                              hipStream_t stream) {
    const int* x     = (const int*)d_in[0];
    const void* mask = d_in[1];
    const int* tags  = (const int*)d_in[2];
    const void* emb  = d_in[3];
    const void* Wihf = d_in[4];
    const void* Whhf = d_in[5];
    const void* bihf = d_in[6];
    const void* bhhf = d_in[7];
    const void* Wihb = d_in[8];
    const void* Whhb = d_in[9];
    const void* bihb = d_in[10];
    const void* bhhb = d_in[11];
    const void* fcW  = d_in[12];
    const void* fcb  = d_in[13];
    const void* trans= d_in[14];

    char* ws = (char*)d_ws;
    u32*   flags = (u32*)(ws + 0);                // 256
    u16*   Wpad  = (u16*)(ws + 256);              // 655,360
    u32*   Whh2  = (u32*)(ws + 655616);           // 262,144 (f16x2 packed)
    float* biasc = (float*)(ws + 917760);         // 4,096
    u16*   fcWc  = (u16*)(ws + 921856);           // 10,240
    float* fcbf  = (float*)(ws + 932096);         // 128
    float* transf= (float*)(ws + 932224);         // 1,664
    u16*   hf    = (u16*)(ws + 933888);           // 8,388,608
    u16*   hb    = (u16*)(ws + 9322496);          // 8,388,608
    float* lgf   = (float*)(ws + 17711104);       // 2,621,440
    float* den   = (float*)(ws + 20332544);       // 256
    float* carry = (float*)(ws + 20332800);       // 131,072
    float* Mc    = (float*)(ws + 20463872);       // 3,276,800
    float* numb  = (float*)(ws + 23740672);       // 256
    const size_t xw_off = 23740928;

    int TC, lg2;
    if (ws_size >= xw_off + 2ull * 65536ull * 512ull + 4096ull)      { TC = 512; lg2 = 9; }
    else if (ws_size >= xw_off + 2ull * 65536ull * 256ull + 4096ull) { TC = 256; lg2 = 8; }
    else if (ws_size >= xw_off + 2ull * 65536ull * 128ull + 4096ull) { TC = 128; lg2 = 7; }
    else if (ws_size >= xw_off + 2ull * 65536ull * 64ull + 4096ull)  { TC = 64;  lg2 = 6; }
    else                                                             { TC = 32;  lg2 = 5; }
    u16* xwf = (u16*)(ws + xw_off);
    u16* xwb = (u16*)(ws + xw_off + (size_t)65536 * TC);

    hipLaunchKernelGGL(sniff_kernel, dim3(1), dim3(64), 0, stream,
                       (const u32*)emb, (const u32*)mask, flags);
    hipLaunchKernelGGL(prep_kernel, dim3(1562), dim3(256), 0, stream,
                       Wihf, Wihb, Whhf, Whhb, bihf, bhhf, bihb, bhhb,
                       fcW, fcb, trans, flags, Wpad, Whh2, biasc, fcWc, fcbf, transf);

    const int nc = T_ / TC;
    for (int ci = 0; ci < nc; ++ci) {
        int t0f = ci * TC;
        int t0b = T_ - 1 - ci * TC;
        hipLaunchKernelGGL(gemm_xw, dim3((B_ * TC) / 128, 4, 2), dim3(256), 0, stream,
                           x, emb, Wpad, biasc, flags, xwf, xwb, lg2, t0f, t0b);
        hipLaunchKernelGGL(lstm_kernel, dim3(B_, 2), dim3(512), 0, stream,
                           Whh2, xwf, xwb, hf, hb, carry, TC, t0f, t0b, (ci == 0) ? 1 : 0);
    }

    hipLaunchKernelGGL(fc_kernel, dim3(512), dim3(256), 0, stream,
                       hf, hb, fcWc, fcbf, flags, lgf, d_out);
    hipLaunchKernelGGL(crf_chunk, dim3(NCH_, B_), dim3(512), 0, stream,
                       lgf, mask, transf, flags, Mc);
    hipLaunchKernelGGL(crf_combine, dim3(B_), dim3(64), 0, stream, lgf, Mc, den);
    hipLaunchKernelGGL(loss_partial, dim3(B_), dim3(64), 0, stream,
                       lgf, mask, tags, transf, flags, numb);
    hipLaunchKernelGGL(loss_final, dim3(1), dim3(64), 0, stream, den, numb, flags, d_out);
}